// Round 22
// baseline (153.890 us; speedup 1.0000x reference)
//
#include <hip/hip_runtime.h>
#include <cstdint>
#include <cstddef>

typedef __attribute__((ext_vector_type(8))) short short8;
typedef __attribute__((ext_vector_type(4))) float floatx4;
typedef __attribute__((ext_vector_type(4))) unsigned short ushort4v;

#define NB 2
#define NPIX 2304
#define TBL 9025
#define TBLP 9032                      // padded to 8 for short8 copies
#define L2E 1.4426950408889634f
#define QSCALE 0.17677669529663689f    // 1/sqrt(32)
#define NTILES 36

__device__ __forceinline__ float b2f(unsigned short u) {
  union { unsigned int i; float f; } v; v.i = ((unsigned int)u) << 16; return v.f;
}
__device__ __forceinline__ float bits2f(unsigned int i) {
  union { unsigned int i; float f; } v; v.i = i; return v.f;
}
__device__ __forceinline__ unsigned short f2b(float f) {
  union { float f; unsigned int i; } v; v.f = f;
  return (unsigned short)((v.i + 0x7fffu + ((v.i >> 16) & 1u)) >> 16);
}
// packed RNE f32->bf16 pair: low 16 = lo, high 16 = hi
__device__ __forceinline__ unsigned int cvtpk(float lo, float hi) {
  unsigned int r;
  asm("v_cvt_pk_bf16_f32 %0, %1, %2" : "=v"(r) : "v"(lo), "v"(hi));
  return r;
}

// ---------------------------------------------------------------------------
// Prep (R16/R18/R19-measured, byte-identical): fp32->bf16 weight conversion +
// per-head bias table gather (pre-scaled by log2(e)).  tabt[h][e], stride TBLP.
// ---------------------------------------------------------------------------
__global__ __launch_bounds__(256) void prep_k(
    const float* __restrict__ gamma, const float* __restrict__ wqkv,
    const float* __restrict__ wout, const float* __restrict__ table,
    unsigned short* __restrict__ gb, unsigned short* __restrict__ qb,
    unsigned short* __restrict__ wb, unsigned short* __restrict__ tb)
{
  int i = blockIdx.x * 256 + threadIdx.x;
  if (i < 65536)  gb[i] = f2b(gamma[i]);
  if (i < 196608) qb[i] = f2b(wqkv[i]);
  if (i < 65536)  wb[i] = f2b(wout[i]);
  if (i < TBL * 8) {
    int e = i >> 3, h = i & 7;
    tb[(size_t)h * TBLP + e] = f2b(table[i] * L2E);
  }
}

// ---------------------------------------------------------------------------
// 64x64-tile bf16 MFMA GEMM, K=256, LDS-staged + issue-early prefetch
// (R18/R19-measured, byte-identical: residue-88.6 pipeline).
// MODE 0: norm = gamma @ x^2   -> xn = x*rsqrt(beta+norm), store xn^T [b][n][c]
// MODE 1: qkv  = w_qkv @ xn    -> q(*QSCALE*L2E)/k [b][h][n][32]; v TRANSPOSED [b][h][32][n]
// MODE 2: out  = w_out @ res^T + b_out -> FP32 [b][c][n]
// ---------------------------------------------------------------------------
template<int MODE>
__global__ __launch_bounds__(256) void gemm_k(
    const unsigned short* __restrict__ A,   // [M][256] bf16 weights
    const void* __restrict__ Bv,            // MODE0: fp32 x [b][256][2304]; else bf16 [b][2304][256]
    const float* __restrict__ vec,          // beta (MODE0) / b_out (MODE2)
    unsigned short* __restrict__ o0,
    unsigned short* __restrict__ o1,
    unsigned short* __restrict__ o2,
    float* __restrict__ of)
{
  __shared__ unsigned short Al[64][40];
  __shared__ unsigned short Bl[64][40];
  const float* __restrict__ X = (const float*)Bv;                    // MODE 0
  const unsigned short* __restrict__ Bw = (const unsigned short*)Bv; // MODE 1/2

  const int n0 = blockIdx.x * 64;
  const int m0 = blockIdx.y * 64;
  const int b  = blockIdx.z;
  const int tid = threadIdx.x;
  const int wave = tid >> 6, lane = tid & 63;
  const int wm = wave >> 1, wn = wave & 1;
  const int lm = lane & 15, quad = lane >> 4;

  // staging coordinates (fixed per thread)
  const int ml = tid >> 2, ko = (tid & 3) * 8;        // A: row ml, k-offset ko
  const int kkB = tid >> 3, n8 = (tid & 7) * 8;       // MODE0 B: k row, n group
  const int nl = tid >> 2;                            // MODE1/2 B: n row (ko reused)

  // prologue: prefetch K-step 0 into registers
  short8 areg = *(const short8*)&A[(size_t)(m0 + ml) * 256 + ko];
  short8 bregs;
  float4 bx0, bx1;
  if (MODE == 0) {
    const float* xr = &X[((size_t)(b * 256 + kkB)) * NPIX + n0 + n8];
    bx0 = *(const float4*)xr;
    bx1 = *(const float4*)(xr + 4);
  } else {
    bregs = *(const short8*)&Bw[((size_t)b * NPIX + n0 + nl) * 256 + ko];
  }

  floatx4 acc[2][2] = {};

  for (int k0 = 0; k0 < 256; k0 += 32) {
    __syncthreads();   // prior iteration's fragment reads complete; LDS free
    *(short8*)&Al[ml][ko] = areg;
    if (MODE == 0) {
      Bl[n8 + 0][kkB] = f2b(bx0.x * bx0.x);
      Bl[n8 + 1][kkB] = f2b(bx0.y * bx0.y);
      Bl[n8 + 2][kkB] = f2b(bx0.z * bx0.z);
      Bl[n8 + 3][kkB] = f2b(bx0.w * bx0.w);
      Bl[n8 + 4][kkB] = f2b(bx1.x * bx1.x);
      Bl[n8 + 5][kkB] = f2b(bx1.y * bx1.y);
      Bl[n8 + 6][kkB] = f2b(bx1.z * bx1.z);
      Bl[n8 + 7][kkB] = f2b(bx1.w * bx1.w);
    } else {
      *(short8*)&Bl[nl][ko] = bregs;
    }
    __syncthreads();   // staging visible

    // issue NEXT K-step's global loads -- latency hidden under MFMA phase
    if (k0 + 32 < 256) {
      areg = *(const short8*)&A[(size_t)(m0 + ml) * 256 + (k0 + 32) + ko];
      if (MODE == 0) {
        const float* xr = &X[((size_t)(b * 256 + (k0 + 32) + kkB)) * NPIX + n0 + n8];
        bx0 = *(const float4*)xr;
        bx1 = *(const float4*)(xr + 4);
      } else {
        bregs = *(const short8*)&Bw[((size_t)b * NPIX + n0 + nl) * 256 + (k0 + 32) + ko];
      }
    }

    short8 af[2], bfr[2];
    #pragma unroll
    for (int tm = 0; tm < 2; ++tm)
      af[tm] = *(const short8*)&Al[wm*32 + tm*16 + lm][quad*8];
    #pragma unroll
    for (int tn = 0; tn < 2; ++tn)
      bfr[tn] = *(const short8*)&Bl[wn*32 + tn*16 + lm][quad*8];
    #pragma unroll
    for (int tm = 0; tm < 2; ++tm)
      #pragma unroll
      for (int tn = 0; tn < 2; ++tn)
        acc[tm][tn] = __builtin_amdgcn_mfma_f32_16x16x32_bf16(af[tm], bfr[tn], acc[tm][tn], 0, 0, 0);
  }

  // epilogue: D[row][col], row = quad*4+reg (+tile), col = lane&15 (+tile)
  #pragma unroll
  for (int tm = 0; tm < 2; ++tm) {
    const int rbase = m0 + wm*32 + tm*16 + quad*4;
    #pragma unroll
    for (int tn = 0; tn < 2; ++tn) {
      const int col = n0 + wn*32 + tn*16 + lm;
      floatx4 a4 = acc[tm][tn];
      if (MODE == 0) {
        ushort4v pk;
        #pragma unroll
        for (int r = 0; r < 4; ++r) {
          int d = rbase + r;
          float xv = X[((size_t)(b * 256 + d)) * NPIX + col];
          pk[r] = f2b(xv * rsqrtf(vec[d] + a4[r]));
        }
        *(ushort4v*)&o0[((size_t)(b * NPIX + col)) * 256 + rbase] = pk;
      } else if (MODE == 1) {
        const int part = rbase >> 8, h = (rbase >> 5) & 7, dd = rbase & 31;
        if (part == 2) {           // V transposed: [b][h][d][n]
          #pragma unroll
          for (int r = 0; r < 4; ++r)
            o2[(((size_t)(b * 8 + h)) * 32 + dd + r) * NPIX + col] = f2b(a4[r]);
        } else {
          unsigned short* dst = part == 0 ? o0 : o1;
          const float sc = (part == 0) ? (QSCALE * L2E) : 1.0f;
          ushort4v pk;
          #pragma unroll
          for (int r = 0; r < 4; ++r) pk[r] = f2b(a4[r] * sc);
          *(ushort4v*)&dst[(((size_t)(b * 8 + h)) * NPIX + col) * 32 + dd] = pk;
        }
      } else {
        #pragma unroll
        for (int r = 0; r < 4; ++r) {
          int c = rbase + r;
          of[((size_t)(b * 256 + c)) * NPIX + col] = a4[r] + vec[c];
        }
      }
    }
  }
}

// ---------------------------------------------------------------------------
// Attention: R19-MEASURED body (bpermute P-redistribution, V-early, no
// K-prefetch -- that lever miscompiled twice, R20/R21, and is abandoned)
// with ONE zero-numerics delta: s_setprio(1/0) around the MFMA clusters
// (guide T5: +4-7% measured on attention in exactly this regime -- many
// barrier-free waves per CU at different phases).
// Grid 256 blocks, 9 waves, one round; LDS = tab only (18.1 KB).
// ---------------------------------------------------------------------------
__global__ __launch_bounds__(576) void attn_k(
    const unsigned short* __restrict__ qg, const unsigned short* __restrict__ kg,
    const unsigned short* __restrict__ vt, const unsigned short* __restrict__ tabt,
    unsigned short* __restrict__ ob)
{
  __shared__ __align__(16) unsigned short tab[TBLP];     // 18.06 KB (only LDS)

  const int tid = threadIdx.x;
  const int lane = tid & 63;
  const int lm = lane & 15, quad = lane >> 4;
  const int w = tid >> 6;
  const int bh = blockIdx.x;
  const int q0 = blockIdx.y * 144;
  const size_t base = (size_t)bh * NPIX * 32;   // q/k base; also vt base

  { // stage per-head bias slice (already *L2E, bf16); TBLP = 8*1129
    const unsigned short* src = tabt + (size_t)(bh & 7) * TBLP;
    for (int e = tid * 8; e < TBLP; e += 4608)
      *(short8*)&tab[e] = *(const short8*)&src[e];
  }
  __syncthreads();   // only barrier in the kernel

  // Q fragment: B-operand for S^T (n=lm=q, k=quad*8+j=d); pre-scaled QSCALE*L2E
  const int q = q0 + w * 16 + lm;
  const short8 qfrag = *(const short8*)&qg[base + (size_t)q * 32 + quad * 8];

  // bias row base for this lane's query
  const int hi = (q * 43691) >> 21;                  // q / 48
  const int rb = (hi + 47) * 95 + (q - hi * 48) + 47;

  // per-lane pointer accumulators (advance per tile: K +2048 elems, V +64)
  const unsigned short* pk0 = kg + base + (size_t)lm * 32 + quad * 8;
  const unsigned short* pv0 = vt + base + (size_t)lm * NPIX + quad * 8;

  // bpermute source-lane byte addresses (fixed per lane)
  const int la4 = (lm + ((quad & 1) << 5)) << 2;     // lane lm + 32*(quad&1)
  const int lb4 = la4 + 64;                          // +16 lanes
  const bool hsel = (quad & 2) != 0;                 // quad>>1

  float lsum = 0.f;
  floatx4 o[2] = {};

  for (int t = 0; t < NTILES; ++t) {
    const int j0 = t * 64;
    // S^T[key][q]: rows = keys (quad*4+r per kt), cols = queries (lm)
    floatx4 s4[4];
    __builtin_amdgcn_s_setprio(1);
    #pragma unroll
    for (int kt = 0; kt < 4; ++kt) {
      short8 kf = *(const short8*)(pk0 + kt * 512);
      floatx4 z = {};
      s4[kt] = __builtin_amdgcn_mfma_f32_16x16x32_bf16(kf, qfrag, z, 0, 0, 0);
    }
    __builtin_amdgcn_s_setprio(0);
    // V fragments EARLY -- independent of P; L2 latency overlaps softmax
    short8 vf[2][2];
    #pragma unroll
    for (int c = 0; c < 2; ++c)
      #pragma unroll
      for (int dt = 0; dt < 2; ++dt)
        vf[c][dt] = *(const short8*)(pv0 + dt * 16 * NPIX + c * 32);

    // softmax: bias (one 8B LDS load/kt, contiguous desc), raw v_exp,
    // pack to cvtpk dwords kept in registers
    unsigned int pkx[4], pky[4];
    #pragma unroll
    for (int kt = 0; kt < 4; ++kt) {
      const int kk = j0 + kt * 16 + quad * 4;
      const int hj = (kk * 43691) >> 21;             // = key/48 for all 4 keys
      const int bb = rb - kk - hj * 47;              // tab idx for r=0
      uint2 bv;
      __builtin_memcpy(&bv, &tab[bb - 3], 8);        // val[j] = tab[bb-3+j]
      float p0 = __builtin_amdgcn_exp2f(s4[kt][0] + bits2f(bv.y & 0xFFFF0000u));
      float p1 = __builtin_amdgcn_exp2f(s4[kt][1] + bits2f(bv.y << 16));
      float p2 = __builtin_amdgcn_exp2f(s4[kt][2] + bits2f(bv.x & 0xFFFF0000u));
      float p3 = __builtin_amdgcn_exp2f(s4[kt][3] + bits2f(bv.x << 16));
      lsum += (p0 + p1) + (p2 + p3);
      pkx[kt] = cvtpk(p0, p1);
      pky[kt] = cvtpk(p2, p3);
    }

    // in-register P redistribution + PV MFMA
    #pragma unroll
    for (int c = 0; c < 2; ++c) {
      int a0 = __builtin_amdgcn_ds_bpermute(la4, (int)pkx[2*c]);
      int b0 = __builtin_amdgcn_ds_bpermute(la4, (int)pkx[2*c+1]);
      int a1 = __builtin_amdgcn_ds_bpermute(la4, (int)pky[2*c]);
      int b1 = __builtin_amdgcn_ds_bpermute(la4, (int)pky[2*c+1]);
      int a2 = __builtin_amdgcn_ds_bpermute(lb4, (int)pkx[2*c]);
      int b2 = __builtin_amdgcn_ds_bpermute(lb4, (int)pkx[2*c+1]);
      int a3 = __builtin_amdgcn_ds_bpermute(lb4, (int)pky[2*c]);
      int b3 = __builtin_amdgcn_ds_bpermute(lb4, (int)pky[2*c+1]);
      union { unsigned int u[4]; short8 s; } pf;
      pf.u[0] = (unsigned int)(hsel ? b0 : a0);
      pf.u[1] = (unsigned int)(hsel ? b1 : a1);
      pf.u[2] = (unsigned int)(hsel ? b2 : a2);
      pf.u[3] = (unsigned int)(hsel ? b3 : a3);
      __builtin_amdgcn_s_setprio(1);
      #pragma unroll
      for (int dt = 0; dt < 2; ++dt)
        o[dt] = __builtin_amdgcn_mfma_f32_16x16x32_bf16(vf[c][dt], pf.s, o[dt], 0, 0, 0);
      __builtin_amdgcn_s_setprio(0);
    }
    pk0 += 2048;   // next 64 keys x 32 d
    pv0 += 64;     // next 64 keys within V^T rows
  }

  // reduce l across the 4 quads holding the same query
  lsum += __shfl_xor(lsum, 16, 64);
  lsum += __shfl_xor(lsum, 32, 64);
  const float inv = 1.f / lsum;

  // store O[q][d] bf16: lane holds d = dt*16 + quad*4 + r at its query q
  #pragma unroll
  for (int dt = 0; dt < 2; ++dt) {
    uint2 pk = { cvtpk(o[dt][0] * inv, o[dt][1] * inv),
                 cvtpk(o[dt][2] * inv, o[dt][3] * inv) };
    *(uint2*)&ob[base + (size_t)q * 32 + dt * 16 + quad * 4] = pk;
  }
}

// ---------------------------------------------------------------------------
extern "C" void kernel_launch(void* const* d_in, const int* in_sizes, int n_in,
                              void* d_out, int out_size, void* d_ws, size_t ws_size,
                              hipStream_t stream) {
  const float* x     = (const float*)d_in[0];
  const float* beta  = (const float*)d_in[1];
  const float* gamma = (const float*)d_in[2];
  const float* wqkv  = (const float*)d_in[3];
  const float* wout  = (const float*)d_in[4];
  const float* bout  = (const float*)d_in[5];
  const float* table = (const float*)d_in[6];
  float* out = (float*)d_out;   // reference output dtype is float32

  unsigned short* ws = (unsigned short*)d_ws;
  const size_t NE = (size_t)NB * NPIX * 256;   // 1,179,648 elems per tensor
  unsigned short* xn_t  = ws;                  // [b][n][256] bf16
  unsigned short* qbuf  = ws + NE;             // [b][h][n][32] bf16, *QSCALE*L2E
  unsigned short* kbuf  = ws + 2 * NE;         // [b][h][n][32]
  unsigned short* vtbuf = ws + 3 * NE;         // [b][h][32][n]  (transposed)
  unsigned short* obuf  = ws + 4 * NE;         // [b][h][n][32] == res[b][n2][e]
  // bf16 weights: gamma/wqkv alias obuf (dead before attn writes it)
  unsigned short* gam_b = obuf;                // 65536
  unsigned short* qkv_b = obuf + 65536;        // 196608 (fits in NE)
  unsigned short* out_b = ws + 5 * NE;         // 65536 (live through gemm2)
  unsigned short* tab_t = ws + 5 * NE + 65536; // 8*TBLP (live through attn)

  prep_k<<<768, 256, 0, stream>>>(gamma, wqkv, wout, table, gam_b, qkv_b, out_b, tab_t);
  gemm_k<0><<<dim3(36, 4, 2), 256, 0, stream>>>(gam_b, x, beta, xn_t, nullptr, nullptr, nullptr);
  gemm_k<1><<<dim3(36, 12, 2), 256, 0, stream>>>(qkv_b, xn_t, nullptr, qbuf, kbuf, vtbuf, nullptr);
  attn_k<<<dim3(16, 16), 576, 0, stream>>>(qbuf, kbuf, vtbuf, tab_t, obuf);
  gemm_k<2><<<dim3(36, 4, 2), 256, 0, stream>>>(out_b, obuf, bout, nullptr, nullptr, nullptr, out);
}

// Round 23
// 151.320 us; speedup vs baseline: 1.0170x; 1.0170x over previous
//
#include <hip/hip_runtime.h>
#include <cstdint>
#include <cstddef>

typedef __attribute__((ext_vector_type(8))) short short8;
typedef __attribute__((ext_vector_type(4))) float floatx4;
typedef __attribute__((ext_vector_type(4))) unsigned short ushort4v;

#define NB 2
#define NPIX 2304
#define TBL 9025
#define TBLP 9032                      // padded to 8 for short8 copies
#define L2E 1.4426950408889634f
#define QSCALE 0.17677669529663689f    // 1/sqrt(32)
#define NTILES 36

__device__ __forceinline__ float b2f(unsigned short u) {
  union { unsigned int i; float f; } v; v.i = ((unsigned int)u) << 16; return v.f;
}
__device__ __forceinline__ float bits2f(unsigned int i) {
  union { unsigned int i; float f; } v; v.i = i; return v.f;
}
__device__ __forceinline__ unsigned short f2b(float f) {
  union { float f; unsigned int i; } v; v.f = f;
  return (unsigned short)((v.i + 0x7fffu + ((v.i >> 16) & 1u)) >> 16);
}
// packed RNE f32->bf16 pair: low 16 = lo, high 16 = hi
__device__ __forceinline__ unsigned int cvtpk(float lo, float hi) {
  unsigned int r;
  asm("v_cvt_pk_bf16_f32 %0, %1, %2" : "=v"(r) : "v"(lo), "v"(hi));
  return r;
}

// ---------------------------------------------------------------------------
// Prep (R16/R18-measured, byte-identical): fp32->bf16 weight conversion +
// per-head bias table gather (pre-scaled by log2(e)).  tabt[h][e], stride TBLP.
// ---------------------------------------------------------------------------
__global__ __launch_bounds__(256) void prep_k(
    const float* __restrict__ gamma, const float* __restrict__ wqkv,
    const float* __restrict__ wout, const float* __restrict__ table,
    unsigned short* __restrict__ gb, unsigned short* __restrict__ qb,
    unsigned short* __restrict__ wb, unsigned short* __restrict__ tb)
{
  int i = blockIdx.x * 256 + threadIdx.x;
  if (i < 65536)  gb[i] = f2b(gamma[i]);
  if (i < 196608) qb[i] = f2b(wqkv[i]);
  if (i < 65536)  wb[i] = f2b(wout[i]);
  if (i < TBL * 8) {
    int e = i >> 3, h = i & 7;
    tb[(size_t)h * TBLP + e] = f2b(table[i] * L2E);
  }
}

// ---------------------------------------------------------------------------
// 64x64-tile bf16 MFMA GEMM, K=256, LDS-staged + issue-early prefetch
// (R18-measured, byte-identical: residue-88.6 pipeline).
// MODE 0: norm = gamma @ x^2   -> xn = x*rsqrt(beta+norm), store xn^T [b][n][c]
// MODE 1: qkv  = w_qkv @ xn    -> q(*QSCALE*L2E)/k [b][h][n][32]; v TRANSPOSED [b][h][32][n]
// MODE 2: out  = w_out @ res^T + b_out -> FP32 [b][c][n]
// ---------------------------------------------------------------------------
template<int MODE>
__global__ __launch_bounds__(256) void gemm_k(
    const unsigned short* __restrict__ A,   // [M][256] bf16 weights
    const void* __restrict__ Bv,            // MODE0: fp32 x [b][256][2304]; else bf16 [b][2304][256]
    const float* __restrict__ vec,          // beta (MODE0) / b_out (MODE2)
    unsigned short* __restrict__ o0,
    unsigned short* __restrict__ o1,
    unsigned short* __restrict__ o2,
    float* __restrict__ of)
{
  __shared__ unsigned short Al[64][40];
  __shared__ unsigned short Bl[64][40];
  const float* __restrict__ X = (const float*)Bv;                    // MODE 0
  const unsigned short* __restrict__ Bw = (const unsigned short*)Bv; // MODE 1/2

  const int n0 = blockIdx.x * 64;
  const int m0 = blockIdx.y * 64;
  const int b  = blockIdx.z;
  const int tid = threadIdx.x;
  const int wave = tid >> 6, lane = tid & 63;
  const int wm = wave >> 1, wn = wave & 1;
  const int lm = lane & 15, quad = lane >> 4;

  // staging coordinates (fixed per thread)
  const int ml = tid >> 2, ko = (tid & 3) * 8;        // A: row ml, k-offset ko
  const int kkB = tid >> 3, n8 = (tid & 7) * 8;       // MODE0 B: k row, n group
  const int nl = tid >> 2;                            // MODE1/2 B: n row (ko reused)

  // prologue: prefetch K-step 0 into registers
  short8 areg = *(const short8*)&A[(size_t)(m0 + ml) * 256 + ko];
  short8 bregs;
  float4 bx0, bx1;
  if (MODE == 0) {
    const float* xr = &X[((size_t)(b * 256 + kkB)) * NPIX + n0 + n8];
    bx0 = *(const float4*)xr;
    bx1 = *(const float4*)(xr + 4);
  } else {
    bregs = *(const short8*)&Bw[((size_t)b * NPIX + n0 + nl) * 256 + ko];
  }

  floatx4 acc[2][2] = {};

  for (int k0 = 0; k0 < 256; k0 += 32) {
    __syncthreads();   // prior iteration's fragment reads complete; LDS free
    *(short8*)&Al[ml][ko] = areg;
    if (MODE == 0) {
      Bl[n8 + 0][kkB] = f2b(bx0.x * bx0.x);
      Bl[n8 + 1][kkB] = f2b(bx0.y * bx0.y);
      Bl[n8 + 2][kkB] = f2b(bx0.z * bx0.z);
      Bl[n8 + 3][kkB] = f2b(bx0.w * bx0.w);
      Bl[n8 + 4][kkB] = f2b(bx1.x * bx1.x);
      Bl[n8 + 5][kkB] = f2b(bx1.y * bx1.y);
      Bl[n8 + 6][kkB] = f2b(bx1.z * bx1.z);
      Bl[n8 + 7][kkB] = f2b(bx1.w * bx1.w);
    } else {
      *(short8*)&Bl[nl][ko] = bregs;
    }
    __syncthreads();   // staging visible

    // issue NEXT K-step's global loads -- latency hidden under MFMA phase
    if (k0 + 32 < 256) {
      areg = *(const short8*)&A[(size_t)(m0 + ml) * 256 + (k0 + 32) + ko];
      if (MODE == 0) {
        const float* xr = &X[((size_t)(b * 256 + (k0 + 32) + kkB)) * NPIX + n0 + n8];
        bx0 = *(const float4*)xr;
        bx1 = *(const float4*)(xr + 4);
      } else {
        bregs = *(const short8*)&Bw[((size_t)b * NPIX + n0 + nl) * 256 + (k0 + 32) + ko];
      }
    }

    short8 af[2], bfr[2];
    #pragma unroll
    for (int tm = 0; tm < 2; ++tm)
      af[tm] = *(const short8*)&Al[wm*32 + tm*16 + lm][quad*8];
    #pragma unroll
    for (int tn = 0; tn < 2; ++tn)
      bfr[tn] = *(const short8*)&Bl[wn*32 + tn*16 + lm][quad*8];
    #pragma unroll
    for (int tm = 0; tm < 2; ++tm)
      #pragma unroll
      for (int tn = 0; tn < 2; ++tn)
        acc[tm][tn] = __builtin_amdgcn_mfma_f32_16x16x32_bf16(af[tm], bfr[tn], acc[tm][tn], 0, 0, 0);
  }

  // epilogue: D[row][col], row = quad*4+reg (+tile), col = lane&15 (+tile)
  #pragma unroll
  for (int tm = 0; tm < 2; ++tm) {
    const int rbase = m0 + wm*32 + tm*16 + quad*4;
    #pragma unroll
    for (int tn = 0; tn < 2; ++tn) {
      const int col = n0 + wn*32 + tn*16 + lm;
      floatx4 a4 = acc[tm][tn];
      if (MODE == 0) {
        ushort4v pk;
        #pragma unroll
        for (int r = 0; r < 4; ++r) {
          int d = rbase + r;
          float xv = X[((size_t)(b * 256 + d)) * NPIX + col];
          pk[r] = f2b(xv * rsqrtf(vec[d] + a4[r]));
        }
        *(ushort4v*)&o0[((size_t)(b * NPIX + col)) * 256 + rbase] = pk;
      } else if (MODE == 1) {
        const int part = rbase >> 8, h = (rbase >> 5) & 7, dd = rbase & 31;
        if (part == 2) {           // V transposed: [b][h][d][n]
          #pragma unroll
          for (int r = 0; r < 4; ++r)
            o2[(((size_t)(b * 8 + h)) * 32 + dd + r) * NPIX + col] = f2b(a4[r]);
        } else {
          unsigned short* dst = part == 0 ? o0 : o1;
          const float sc = (part == 0) ? (QSCALE * L2E) : 1.0f;
          ushort4v pk;
          #pragma unroll
          for (int r = 0; r < 4; ++r) pk[r] = f2b(a4[r] * sc);
          *(ushort4v*)&dst[(((size_t)(b * 8 + h)) * NPIX + col) * 32 + dd] = pk;
        }
      } else {
        #pragma unroll
        for (int r = 0; r < 4; ++r) {
          int c = rbase + r;
          of[((size_t)(b * 256 + c)) * NPIX + col] = a4[r] + vec[c];
        }
      }
    }
  }
}

// ---------------------------------------------------------------------------
// Attention: R18-MEASURED version, byte-identical (62.9us, total 151.46 --
// session best).  setprio reverted (R22 A/B: -2.3us on this lockstep
// structure).  Grid 256 blocks (16 bh x 16 qblk of 144 q), 9 waves, one
// dispatch round.  Wall = per-CU latency-structure plateau: TLP x2 null
// (R13), VALU diet -4.5us only (R16), LDS-drain removal null (R19),
// setprio negative (R22), K-prefetch miscompiles (R20/R21).
// ---------------------------------------------------------------------------
__global__ __launch_bounds__(576) void attn_k(
    const unsigned short* __restrict__ qg, const unsigned short* __restrict__ kg,
    const unsigned short* __restrict__ vt, const unsigned short* __restrict__ tabt,
    unsigned short* __restrict__ ob)
{
  __shared__ __align__(16) unsigned short tab[TBLP];     // 18.06 KB
  __shared__ __align__(16) unsigned short Pl[9][16][72]; // 20.7 KB, per-wave

  const int tid = threadIdx.x;
  const int w = tid >> 6, lane = tid & 63;
  const int lm = lane & 15, quad = lane >> 4;
  const int bh = blockIdx.x;
  const int q0 = blockIdx.y * 144;
  const size_t base = (size_t)bh * NPIX * 32;   // q/k base; also vt base

  { // stage per-head bias slice (already *L2E, bf16); TBLP = 8*1129
    const unsigned short* src = tabt + (size_t)(bh & 7) * TBLP;
    for (int e = tid * 8; e < TBLP; e += 4608)
      *(short8*)&tab[e] = *(const short8*)&src[e];
  }
  __syncthreads();   // only barrier in the kernel

  // Q fragment: B-operand for S^T (n=lm=q, k=quad*8+j=d); pre-scaled QSCALE*L2E
  const int q = q0 + w * 16 + lm;
  const short8 qfrag = *(const short8*)&qg[base + (size_t)q * 32 + quad * 8];

  // bias row base for this lane's query
  const int hi = (q * 43691) >> 21;                  // q / 48
  const int rb = (hi + 47) * 95 + (q - hi * 48) + 47;

  // per-lane pointer accumulators (advance per tile: K +2048 elems, V +64)
  const unsigned short* pk0 = kg + base + (size_t)lm * 32 + quad * 8;
  const unsigned short* pv0 = vt + base + (size_t)lm * NPIX + quad * 8;

  float lsum = 0.f;
  floatx4 o[2] = {};

  for (int t = 0; t < NTILES; ++t) {
    const int j0 = t * 64;
    // S^T[key][q]: rows = keys (quad*4+r per kt), cols = queries (lm)
    floatx4 s4[4];
    #pragma unroll
    for (int kt = 0; kt < 4; ++kt) {
      short8 kf = *(const short8*)(pk0 + kt * 512);
      floatx4 z = {};
      s4[kt] = __builtin_amdgcn_mfma_f32_16x16x32_bf16(kf, qfrag, z, 0, 0, 0);
    }
    // + bias: one 8B load of tab[bb-3..bb] per kt (contiguous, descending in
    // r); extract as float bits directly (b2f == <<16).  exp2 = raw v_exp.
    #pragma unroll
    for (int kt = 0; kt < 4; ++kt) {
      const int kk = j0 + kt * 16 + quad * 4;
      const int hj = (kk * 43691) >> 21;             // = key/48 for all 4 keys
      const int bb = rb - kk - hj * 47;              // tab idx for r=0
      uint2 bv;
      __builtin_memcpy(&bv, &tab[bb - 3], 8);        // val[j] = tab[bb-3+j]
      float p0 = __builtin_amdgcn_exp2f(s4[kt][0] + bits2f(bv.y & 0xFFFF0000u));
      float p1 = __builtin_amdgcn_exp2f(s4[kt][1] + bits2f(bv.y << 16));
      float p2 = __builtin_amdgcn_exp2f(s4[kt][2] + bits2f(bv.x & 0xFFFF0000u));
      float p3 = __builtin_amdgcn_exp2f(s4[kt][3] + bits2f(bv.x << 16));
      lsum += (p0 + p1) + (p2 + p3);
      uint2 pk = { cvtpk(p0, p1), cvtpk(p2, p3) };
      *(uint2*)&Pl[w][lm][kt * 16 + quad * 4] = pk;  // P[q][key] layout
    }
    __asm__ volatile("s_waitcnt lgkmcnt(0)" ::: "memory"); // wave-local DS order
    // O^T[d][q] += V^T[d][key] * P^T[key][q]
    #pragma unroll
    for (int c = 0; c < 2; ++c) {
      short8 pf = *(const short8*)&Pl[w][lm][c * 32 + quad * 8];
      #pragma unroll
      for (int dt = 0; dt < 2; ++dt) {
        short8 vf = *(const short8*)(pv0 + dt * 16 * NPIX + c * 32);
        o[dt] = __builtin_amdgcn_mfma_f32_16x16x32_bf16(vf, pf, o[dt], 0, 0, 0);
      }
    }
    pk0 += 2048;   // next 64 keys x 32 d
    pv0 += 64;     // next 64 keys within V^T rows
  }

  // reduce l across the 4 quads holding the same query
  lsum += __shfl_xor(lsum, 16, 64);
  lsum += __shfl_xor(lsum, 32, 64);
  const float inv = 1.f / lsum;

  // store O[q][d] bf16: lane holds d = dt*16 + quad*4 + r at its query q
  #pragma unroll
  for (int dt = 0; dt < 2; ++dt) {
    uint2 pk = { cvtpk(o[dt][0] * inv, o[dt][1] * inv),
                 cvtpk(o[dt][2] * inv, o[dt][3] * inv) };
    *(uint2*)&ob[base + (size_t)q * 32 + dt * 16 + quad * 4] = pk;
  }
}

// ---------------------------------------------------------------------------
extern "C" void kernel_launch(void* const* d_in, const int* in_sizes, int n_in,
                              void* d_out, int out_size, void* d_ws, size_t ws_size,
                              hipStream_t stream) {
  const float* x     = (const float*)d_in[0];
  const float* beta  = (const float*)d_in[1];
  const float* gamma = (const float*)d_in[2];
  const float* wqkv  = (const float*)d_in[3];
  const float* wout  = (const float*)d_in[4];
  const float* bout  = (const float*)d_in[5];
  const float* table = (const float*)d_in[6];
  float* out = (float*)d_out;   // reference output dtype is float32

  unsigned short* ws = (unsigned short*)d_ws;
  const size_t NE = (size_t)NB * NPIX * 256;   // 1,179,648 elems per tensor
  unsigned short* xn_t  = ws;                  // [b][n][256] bf16
  unsigned short* qbuf  = ws + NE;             // [b][h][n][32] bf16, *QSCALE*L2E
  unsigned short* kbuf  = ws + 2 * NE;         // [b][h][n][32]
  unsigned short* vtbuf = ws + 3 * NE;         // [b][h][32][n]  (transposed)
  unsigned short* obuf  = ws + 4 * NE;         // [b][h][n][32] == res[b][n2][e]
  // bf16 weights: gamma/wqkv alias obuf (dead before attn writes it)
  unsigned short* gam_b = obuf;                // 65536
  unsigned short* qkv_b = obuf + 65536;        // 196608 (fits in NE)
  unsigned short* out_b = ws + 5 * NE;         // 65536 (live through gemm2)
  unsigned short* tab_t = ws + 5 * NE + 65536; // 8*TBLP (live through attn)

  prep_k<<<768, 256, 0, stream>>>(gamma, wqkv, wout, table, gam_b, qkv_b, out_b, tab_t);
  gemm_k<0><<<dim3(36, 4, 2), 256, 0, stream>>>(gam_b, x, beta, xn_t, nullptr, nullptr, nullptr);
  gemm_k<1><<<dim3(36, 12, 2), 256, 0, stream>>>(qkv_b, xn_t, nullptr, qbuf, kbuf, vtbuf, nullptr);
  attn_k<<<dim3(16, 16), 576, 0, stream>>>(qbuf, kbuf, vtbuf, tab_t, obuf);
  gemm_k<2><<<dim3(36, 4, 2), 256, 0, stream>>>(out_b, obuf, bout, nullptr, nullptr, nullptr, out);
}